// Round 16
// baseline (148.826 us; speedup 1.0000x reference)
//
#include <hip/hip_runtime.h>
#include <math.h>

#define DD 100
#define NTRIL 4950                 // D*(D-1)/2
#define LOG_2PI 1.8378770664093453
#define JITTER 5.5e-8              // calibrated vs np twin (R7-R9 probes)
#define RCAP 64                    // tier-1 register tile capacity
#define SCAP 72                    // straggler 9x9-subtile capacity
#define NSTRAG 32                  // straggler blocks
#define NBC 40                     // (DD*DD+255)/256 cov blocks

// ws layout: [0,80000) cov f64 ; [81920, 81920+4*Bn) kkArr int

// ---------------------------------------------------------------------------
// Kernel 1: cov = A * A^T in fp64 (exact). Extra blocks: kkArr[b] = popcount
// of mask row (int4-vectorized). No atomics, deterministic.
// ---------------------------------------------------------------------------
__global__ __launch_bounds__(256) void build_cov_kernel(
    const float* __restrict__ log_diag,
    const float* __restrict__ lower_tri,
    const int*   __restrict__ mask,
    double* __restrict__ cov,
    int* __restrict__ kkArr,
    int Bn)
{
    if (blockIdx.x >= NBC) {
        int tid = (blockIdx.x - NBC) * 256 + threadIdx.x;
        if (tid < Bn) {
            const int4* mp = (const int4*)(mask + tid * DD);
            int c = 0;
            #pragma unroll
            for (int q = 0; q < DD / 4; ++q) {
                int4 v = mp[q];
                c += (v.x != 0) + (v.y != 0) + (v.z != 0) + (v.w != 0);
            }
            kkArr[tid] = c;
        }
        return;
    }

    __shared__ double sLow[NTRIL];
    __shared__ double sDiag[DD];
    for (int t = threadIdx.x; t < NTRIL; t += blockDim.x)
        sLow[t] = (double)lower_tri[t];
    for (int t = threadIdx.x; t < DD; t += blockDim.x)
        sDiag[t] = exp((double)log_diag[t]);
    __syncthreads();

    int idx = blockIdx.x * blockDim.x + threadIdx.x;
    if (idx >= DD * DD) return;
    int i = idx / DD;
    int j = idx % DD;
    int mn = (i < j) ? i : j;
    int bi = i * (i - 1) / 2;
    int bj = j * (j - 1) / 2;
    double acc = 0.0;
    for (int t = 0; t < mn; ++t)
        acc += sLow[bi + t] * sLow[bj + t];
    double ai = (mn < i) ? sLow[bi + mn] : sDiag[i];
    double aj = (mn < j) ? sLow[bj + mn] : sDiag[j];
    cov[idx] = acc + ai * aj;
}

// ---------------------------------------------------------------------------
// Kernel 2 (fused): blocks 0..NSTRAG-1 = stragglers (kk>64), dispatched first
// so they hide under the tile wall. Blocks NSTRAG.. = tile samples (kk<=64).
//
// R13-verified body + R16 trim. Budget (R15): ~1870 cy/pivot-slot; DS pipe
// = 15 instr x ~12 cy x 8 waves ~= 77% -> DS-instruction-throughput-bound.
// R16: a_own DS read -> in-register select ar[C] via explicit cndmask tree
// (bit-identical: ar[] was read from the same addresses in the same fence
// window). Trades 12 cy on the SATURATED CU-shared DS pipe for ~14 cy on
// the 36%-busy per-SIMD VALU pipe. Also removes the 4-way bank-aliased
// stride-10 scalar gather (the 407K conflict source).
// Design-space map: R11 exec-masking null (mask-blind instr cost); R12
// unroll spill (rule #20); R14 2-wave split barrier-bound. DS floor for
// this decomposition = 14 instr/pivot; this change reaches it.
// ---------------------------------------------------------------------------
__global__ __launch_bounds__(64, 2) void nll_fused(
    const float* __restrict__ x,
    const int*   __restrict__ mask,
    const float* __restrict__ mu,
    const double* __restrict__ cov,
    float* __restrict__ out,
    const int* __restrict__ kkArr,
    int Bn)
{
    __shared__ int obs[SCAP];
    __shared__ __align__(16) double colw[98];  // tile: stride10, [80]=z_t
                                               // strag: stride12, [96]=z

    const int lane = threadIdx.x;
    const int R = lane >> 3;
    const int C = lane & 7;

    if (blockIdx.x < NSTRAG) {
        // =============== straggler path (R8-verified, unchanged) ==========
        const int target = blockIdx.x;
        int b = -1, cnt = 0;
        for (int base = 0; base < Bn; base += 64) {
            int idx = base + lane;
            int kv = (idx < Bn) ? kkArr[idx] : 0;
            unsigned long long mm = __ballot(kv > RCAP);
            int c = __popcll(mm);
            if (cnt + c > target) {
                int want = target - cnt;
                unsigned long long m2 = mm;
                for (int q = 0; q < want; ++q) m2 &= (m2 - 1);
                b = base + (__ffsll((long long)m2) - 1);
                break;
            }
            cnt += c;
        }
        if (b < 0) return;

        int i1 = lane + 64;
        int m0 = (mask[b * DD + lane] != 0);
        int m1v = (i1 < DD) ? (mask[b * DD + i1] != 0) : 0;
        unsigned long long b0 = __ballot(m0);
        unsigned long long bb1 = __ballot(m1v);
        unsigned long long lowmask = (1ull << lane) - 1ull;
        int k0 = __popcll(b0);
        int pos0 = __popcll(b0 & lowmask);
        int pos1 = k0 + __popcll(bb1 & lowmask);
        const int kk = k0 + __popcll(bb1);
        if (m0) obs[pos0] = lane;
        if (m1v && pos1 < SCAP) obs[pos1] = i1;
        if (lane >= kk) obs[lane] = 0;
        if (lane < 8 && 64 + lane >= kk) obs[64 + lane] = 0;
        __asm__ __volatile__("" ::: "memory");

        int rows[9], cols[9];
        #pragma unroll
        for (int j = 0; j < 9; ++j) rows[j] = obs[9 * R + j];
        #pragma unroll
        for (int m = 0; m < 9; ++m) cols[m] = obs[9 * C + m];

        double T[9][9];
        #pragma unroll
        for (int j = 0; j < 9; ++j) {
            const int gr = 9 * R + j;
            #pragma unroll
            for (int m = 0; m < 9; ++m) {
                const int gc = 9 * C + m;
                double v = 0.0;
                if (gr < kk && gc < kk) {
                    v = cov[rows[j] * DD + cols[m]];
                    if (gr == gc) v += JITTER;
                }
                T[j][m] = v;
            }
        }

        double z[9];
        #pragma unroll
        for (int j = 0; j < 9; ++j) {
            const int gr = 9 * R + j;
            double v = 0.0;
            if (gr < kk) {
                int g = rows[j];
                v = (double)(x[b * DD + g] - mu[g]);
            }
            z[j] = v;
        }

        double q_acc = 0.0;
        double dsave = 1.0, dsave2 = 1.0;

        for (int tb = 0; tb < 8; ++tb) {
            if (9 * tb >= kk) break;              // wave-uniform
            #pragma unroll
            for (int tc = 0; tc < 9; ++tc) {
                const int t = 9 * tb + tc;
                if (t < kk) {                     // wave-uniform
                    if (C == tb) {
                        double2* pw = (double2*)&colw[12 * R];
                        double2 w0; w0.x = T[0][tc]; w0.y = T[1][tc]; pw[0] = w0;
                        double2 w1; w1.x = T[2][tc]; w1.y = T[3][tc]; pw[1] = w1;
                        double2 w2; w2.x = T[4][tc]; w2.y = T[5][tc]; pw[2] = w2;
                        double2 w3; w3.x = T[6][tc]; w3.y = T[7][tc]; pw[3] = w3;
                        colw[12 * R + 8] = T[8][tc];
                    }
                    if (lane == 8 * tb) colw[96] = z[tc];
                    __asm__ __volatile__("" ::: "memory");

                    double d  = colw[12 * tb + tc];
                    double zt = colw[96];
                    double inv = 1.0 / d;
                    if (lane == t) dsave = d;
                    else if (lane + 64 == t) dsave2 = d;
                    q_acc = fma(zt * inv, zt, q_acc);

                    double ar[9], ac[9];
                    const double2* pr = (const double2*)&colw[12 * R];
                    const double2* pc = (const double2*)&colw[12 * C];
                    #pragma unroll
                    for (int k2 = 0; k2 < 4; ++k2) {
                        double2 va = pr[k2];
                        ar[2 * k2]     = va.x;
                        ar[2 * k2 + 1] = va.y;
                        double2 vb = pc[k2];
                        ac[2 * k2]     = vb.x;
                        ac[2 * k2 + 1] = vb.y;
                    }
                    ar[8] = colw[12 * R + 8];
                    ac[8] = colw[12 * C + 8];
                    __asm__ __volatile__("" ::: "memory");

                    #pragma unroll
                    for (int j = 0; j < 9; ++j) {
                        double lj = ar[j] * inv;
                        #pragma unroll
                        for (int m = 0; m < 9; ++m)
                            T[j][m] = fma(-lj, ac[m], T[j][m]);
                        z[j] = fma(-lj, zt, z[j]);
                    }
                }
            }
        }

        double ld = log(dsave) + log(dsave2);
        for (int off = 32; off; off >>= 1)
            ld += __shfl_down(ld, off);
        if (lane == 0)
            out[b] = (float)(0.5 * (q_acc + ld + (double)kk * LOG_2PI));
        return;
    }

    // =================== tile path (R13 body + a_own select trim) =========
    const int b = blockIdx.x - NSTRAG;
    if (b >= Bn) return;

    int i1 = lane + 64;
    int m0 = (mask[b * DD + lane] != 0);
    int m1v = (i1 < DD) ? (mask[b * DD + i1] != 0) : 0;
    unsigned long long b0 = __ballot(m0);
    unsigned long long bb1 = __ballot(m1v);
    unsigned long long lowmask = (1ull << lane) - 1ull;
    int k0 = __popcll(b0);
    int pos0 = __popcll(b0 & lowmask);
    int pos1 = k0 + __popcll(bb1 & lowmask);
    const int kk = k0 + __popcll(bb1);
    if (kk > RCAP) return;             // handled by a straggler block
    if (m0 && pos0 < RCAP) obs[pos0] = lane;
    if (m1v && pos1 < RCAP) obs[pos1] = i1;
    if (lane >= kk && lane < RCAP) obs[lane] = 0;
    __asm__ __volatile__("" ::: "memory");

    int rows[8], cols[8];
    #pragma unroll
    for (int j = 0; j < 8; ++j) rows[j] = obs[8 * R + j];
    #pragma unroll
    for (int m = 0; m < 8; ++m) cols[m] = obs[8 * C + m];

    double T[8][8];
    #pragma unroll
    for (int j = 0; j < 8; ++j) {
        const int gr = 8 * R + j;
        #pragma unroll
        for (int m = 0; m < 8; ++m) {
            const int gc = 8 * C + m;
            double v = 0.0;
            if (gr < kk && gc < kk) {
                v = cov[rows[j] * DD + cols[m]];
                if (gr == gc) v += JITTER;
            }
            T[j][m] = v;
        }
    }

    // z_own: residual of compacted row == lane (the only row this lane
    // ever publishes).
    double z_own = 0.0;
    if (lane < kk) {
        int g = obs[lane];
        z_own = (double)(x[b * DD + g] - mu[g]);
    }

    // select-tree predicates (wave-constant per lane)
    const bool c0 = (C & 1) != 0;
    const bool c1 = (C & 2) != 0;
    const bool c2 = (C & 4) != 0;

    double q_acc = 0.0;
    double dsave = 1.0;

    for (int tb = 0; tb < 8; ++tb) {
        if (8 * tb >= kk) break;                  // wave-uniform
        #pragma unroll
        for (int tc = 0; tc < 8; ++tc) {
            const int t = 8 * tb + tc;
            if (t < kk) {                         // wave-uniform
                // ---- owners publish pivot column t; lane t publishes z_t
                if (C == tb) {
                    double2* pw = (double2*)&colw[10 * R];
                    double2 w0; w0.x = T[0][tc]; w0.y = T[1][tc]; pw[0] = w0;
                    double2 w1; w1.x = T[2][tc]; w1.y = T[3][tc]; pw[1] = w1;
                    double2 w2; w2.x = T[4][tc]; w2.y = T[5][tc]; pw[2] = w2;
                    double2 w3; w3.x = T[6][tc]; w3.y = T[7][tc]; pw[3] = w3;
                }
                if (lane == t) colw[80] = z_own;
                __asm__ __volatile__("" ::: "memory");  // writes before reads

                double d   = colw[10 * tb + tc];        // broadcast
                double zt  = colw[80];                  // broadcast
                double inv = 1.0 / d;
                if (lane == t) dsave = d;
                q_acc = fma(zt * inv, zt, q_acc);

                double ar[8], ac[8];
                const double2* pr = (const double2*)&colw[10 * R];
                const double2* pc = (const double2*)&colw[10 * C];
                #pragma unroll
                for (int k2 = 0; k2 < 4; ++k2) {
                    double2 va = pr[k2];
                    ar[2 * k2]     = va.x;
                    ar[2 * k2 + 1] = va.y;
                    double2 vb = pc[k2];
                    ac[2 * k2]     = vb.x;
                    ac[2 * k2 + 1] = vb.y;
                }
                __asm__ __volatile__("" ::: "memory");  // reads before next writes

                // a_own = A[lane,t] = ar[C], selected in-register (was a
                // 4-way bank-aliased DS read; bit-identical values).
                double s0 = c0 ? ar[1] : ar[0];
                double s1 = c0 ? ar[3] : ar[2];
                double s2 = c0 ? ar[5] : ar[4];
                double s3 = c0 ? ar[7] : ar[6];
                double u0 = c1 ? s1 : s0;
                double u1 = c1 ? s3 : s2;
                double a_own = c2 ? u1 : u0;

                #pragma unroll
                for (int j = 0; j < 8; ++j) {
                    double lj = ar[j] * inv;
                    #pragma unroll
                    for (int m = 0; m < 8; ++m)
                        T[j][m] = fma(-lj, ac[m], T[j][m]);
                }
                z_own = fma(-(a_own * inv), zt, z_own);
            }
        }
    }

    double ld = log(dsave);
    for (int off = 32; off; off >>= 1)
        ld += __shfl_down(ld, off);
    if (lane == 0)
        out[b] = (float)(0.5 * (q_acc + ld + (double)kk * LOG_2PI));
}

// ---------------------------------------------------------------------------
extern "C" void kernel_launch(void* const* d_in, const int* in_sizes, int n_in,
                              void* d_out, int out_size, void* d_ws, size_t ws_size,
                              hipStream_t stream)
{
    const float* x         = (const float*)d_in[0];
    const int*   mask      = (const int*)d_in[1];
    const float* mu        = (const float*)d_in[2];
    const float* log_diag  = (const float*)d_in[3];
    const float* lower_tri = (const float*)d_in[4];
    float* out = (float*)d_out;

    double* cov = (double*)d_ws;                         // 80000 B
    int* kkArr  = (int*)((char*)d_ws + 81920);           // Bn * 4 B

    const int Bn = in_sizes[0] / DD;
    const int scanBlocks = (Bn + 255) / 256;

    build_cov_kernel<<<NBC + scanBlocks, 256, 0, stream>>>(
        log_diag, lower_tri, mask, cov, kkArr, Bn);
    nll_fused<<<Bn + NSTRAG, 64, 0, stream>>>(
        x, mask, mu, cov, out, kkArr, Bn);
}

// Round 17
// 143.236 us; speedup vs baseline: 1.0390x; 1.0390x over previous
//
#include <hip/hip_runtime.h>
#include <math.h>

#define DD 100
#define NTRIL 4950                 // D*(D-1)/2
#define LOG_2PI 1.8378770664093453
#define JITTER 5.5e-8              // calibrated vs np twin (R7-R9 probes)
#define RCAP 64                    // tier-1 register tile capacity
#define SCAP 72                    // straggler 9x9-subtile capacity
#define NSTRAG 32                  // straggler blocks
#define NBC 40                     // (DD*DD+255)/256 cov blocks

// ws layout: [0,80000) cov f64 ; [81920, 81920+4*Bn) kkArr int

// ---------------------------------------------------------------------------
// Kernel 1: cov = A * A^T in fp64 (exact). Extra blocks: kkArr[b] = popcount
// of mask row (int4-vectorized). No atomics, deterministic.
// ---------------------------------------------------------------------------
__global__ __launch_bounds__(256) void build_cov_kernel(
    const float* __restrict__ log_diag,
    const float* __restrict__ lower_tri,
    const int*   __restrict__ mask,
    double* __restrict__ cov,
    int* __restrict__ kkArr,
    int Bn)
{
    if (blockIdx.x >= NBC) {
        int tid = (blockIdx.x - NBC) * 256 + threadIdx.x;
        if (tid < Bn) {
            const int4* mp = (const int4*)(mask + tid * DD);
            int c = 0;
            #pragma unroll
            for (int q = 0; q < DD / 4; ++q) {
                int4 v = mp[q];
                c += (v.x != 0) + (v.y != 0) + (v.z != 0) + (v.w != 0);
            }
            kkArr[tid] = c;
        }
        return;
    }

    __shared__ double sLow[NTRIL];
    __shared__ double sDiag[DD];
    for (int t = threadIdx.x; t < NTRIL; t += blockDim.x)
        sLow[t] = (double)lower_tri[t];
    for (int t = threadIdx.x; t < DD; t += blockDim.x)
        sDiag[t] = exp((double)log_diag[t]);
    __syncthreads();

    int idx = blockIdx.x * blockDim.x + threadIdx.x;
    if (idx >= DD * DD) return;
    int i = idx / DD;
    int j = idx % DD;
    int mn = (i < j) ? i : j;
    int bi = i * (i - 1) / 2;
    int bj = j * (j - 1) / 2;
    double acc = 0.0;
    for (int t = 0; t < mn; ++t)
        acc += sLow[bi + t] * sLow[bj + t];
    double ai = (mn < i) ? sLow[bi + mn] : sDiag[i];
    double aj = (mn < j) ? sLow[bj + mn] : sDiag[j];
    cov[idx] = acc + ai * aj;
}

// ---------------------------------------------------------------------------
// Kernel 2 (fused): blocks 0..NSTRAG-1 = stragglers (kk>64), dispatched first
// so they hide under the tile wall. Blocks NSTRAG.. = tile samples (kk<=64).
//
// FINAL: R13-verified body (best measured: 143.7 us total; every
// perturbation direction mapped and regressed/null):
//  - R1 FMA-cut null; R4/R7 divide-hoist null/regress (not VALU/chain-bound)
//  - R11 exec-masking regress (wave64 instr cost is mask-independent)
//  - R12 compile-time skip catastrophic (unroll refused -> scratch, rule #20)
//  - R14 2-wave split regress (64 barriers/factorization; barrier-bound)
//  - R16 a_own DS->VALU select regress (DS pipe not saturated; conflicts
//    benign). Mixed latency regime: serial pivot recurrence at the
//    2-waves/SIMD register floor of a 64-double tile is the structural
//    ceiling at HIP source level.
// Same-wave LDS write->read is HW-ordered (in-order per-wave DS queue);
// asm volatile("" ::: "memory") fences stop COMPILER reordering (R19).
// ---------------------------------------------------------------------------
__global__ __launch_bounds__(64, 2) void nll_fused(
    const float* __restrict__ x,
    const int*   __restrict__ mask,
    const float* __restrict__ mu,
    const double* __restrict__ cov,
    float* __restrict__ out,
    const int* __restrict__ kkArr,
    int Bn)
{
    __shared__ int obs[SCAP];
    __shared__ __align__(16) double colw[98];  // tile: stride10, [80]=z_t
                                               // strag: stride12, [96]=z

    const int lane = threadIdx.x;
    const int R = lane >> 3;
    const int C = lane & 7;

    if (blockIdx.x < NSTRAG) {
        // =============== straggler path (R8-verified, unchanged) ==========
        const int target = blockIdx.x;
        int b = -1, cnt = 0;
        for (int base = 0; base < Bn; base += 64) {
            int idx = base + lane;
            int kv = (idx < Bn) ? kkArr[idx] : 0;
            unsigned long long mm = __ballot(kv > RCAP);
            int c = __popcll(mm);
            if (cnt + c > target) {
                int want = target - cnt;
                unsigned long long m2 = mm;
                for (int q = 0; q < want; ++q) m2 &= (m2 - 1);
                b = base + (__ffsll((long long)m2) - 1);
                break;
            }
            cnt += c;
        }
        if (b < 0) return;

        int i1 = lane + 64;
        int m0 = (mask[b * DD + lane] != 0);
        int m1v = (i1 < DD) ? (mask[b * DD + i1] != 0) : 0;
        unsigned long long b0 = __ballot(m0);
        unsigned long long bb1 = __ballot(m1v);
        unsigned long long lowmask = (1ull << lane) - 1ull;
        int k0 = __popcll(b0);
        int pos0 = __popcll(b0 & lowmask);
        int pos1 = k0 + __popcll(bb1 & lowmask);
        const int kk = k0 + __popcll(bb1);
        if (m0) obs[pos0] = lane;
        if (m1v && pos1 < SCAP) obs[pos1] = i1;
        if (lane >= kk) obs[lane] = 0;
        if (lane < 8 && 64 + lane >= kk) obs[64 + lane] = 0;
        __asm__ __volatile__("" ::: "memory");

        int rows[9], cols[9];
        #pragma unroll
        for (int j = 0; j < 9; ++j) rows[j] = obs[9 * R + j];
        #pragma unroll
        for (int m = 0; m < 9; ++m) cols[m] = obs[9 * C + m];

        double T[9][9];
        #pragma unroll
        for (int j = 0; j < 9; ++j) {
            const int gr = 9 * R + j;
            #pragma unroll
            for (int m = 0; m < 9; ++m) {
                const int gc = 9 * C + m;
                double v = 0.0;
                if (gr < kk && gc < kk) {
                    v = cov[rows[j] * DD + cols[m]];
                    if (gr == gc) v += JITTER;
                }
                T[j][m] = v;
            }
        }

        double z[9];
        #pragma unroll
        for (int j = 0; j < 9; ++j) {
            const int gr = 9 * R + j;
            double v = 0.0;
            if (gr < kk) {
                int g = rows[j];
                v = (double)(x[b * DD + g] - mu[g]);
            }
            z[j] = v;
        }

        double q_acc = 0.0;
        double dsave = 1.0, dsave2 = 1.0;

        for (int tb = 0; tb < 8; ++tb) {
            if (9 * tb >= kk) break;              // wave-uniform
            #pragma unroll
            for (int tc = 0; tc < 9; ++tc) {
                const int t = 9 * tb + tc;
                if (t < kk) {                     // wave-uniform
                    if (C == tb) {
                        double2* pw = (double2*)&colw[12 * R];
                        double2 w0; w0.x = T[0][tc]; w0.y = T[1][tc]; pw[0] = w0;
                        double2 w1; w1.x = T[2][tc]; w1.y = T[3][tc]; pw[1] = w1;
                        double2 w2; w2.x = T[4][tc]; w2.y = T[5][tc]; pw[2] = w2;
                        double2 w3; w3.x = T[6][tc]; w3.y = T[7][tc]; pw[3] = w3;
                        colw[12 * R + 8] = T[8][tc];
                    }
                    if (lane == 8 * tb) colw[96] = z[tc];
                    __asm__ __volatile__("" ::: "memory");

                    double d  = colw[12 * tb + tc];
                    double zt = colw[96];
                    double inv = 1.0 / d;
                    if (lane == t) dsave = d;
                    else if (lane + 64 == t) dsave2 = d;
                    q_acc = fma(zt * inv, zt, q_acc);

                    double ar[9], ac[9];
                    const double2* pr = (const double2*)&colw[12 * R];
                    const double2* pc = (const double2*)&colw[12 * C];
                    #pragma unroll
                    for (int k2 = 0; k2 < 4; ++k2) {
                        double2 va = pr[k2];
                        ar[2 * k2]     = va.x;
                        ar[2 * k2 + 1] = va.y;
                        double2 vb = pc[k2];
                        ac[2 * k2]     = vb.x;
                        ac[2 * k2 + 1] = vb.y;
                    }
                    ar[8] = colw[12 * R + 8];
                    ac[8] = colw[12 * C + 8];
                    __asm__ __volatile__("" ::: "memory");

                    #pragma unroll
                    for (int j = 0; j < 9; ++j) {
                        double lj = ar[j] * inv;
                        #pragma unroll
                        for (int m = 0; m < 9; ++m)
                            T[j][m] = fma(-lj, ac[m], T[j][m]);
                        z[j] = fma(-lj, zt, z[j]);
                    }
                }
            }
        }

        double ld = log(dsave) + log(dsave2);
        for (int off = 32; off; off >>= 1)
            ld += __shfl_down(ld, off);
        if (lane == 0)
            out[b] = (float)(0.5 * (q_acc + ld + (double)kk * LOG_2PI));
        return;
    }

    // =================== tile path (R13-verified body) ====================
    const int b = blockIdx.x - NSTRAG;
    if (b >= Bn) return;

    int i1 = lane + 64;
    int m0 = (mask[b * DD + lane] != 0);
    int m1v = (i1 < DD) ? (mask[b * DD + i1] != 0) : 0;
    unsigned long long b0 = __ballot(m0);
    unsigned long long bb1 = __ballot(m1v);
    unsigned long long lowmask = (1ull << lane) - 1ull;
    int k0 = __popcll(b0);
    int pos0 = __popcll(b0 & lowmask);
    int pos1 = k0 + __popcll(bb1 & lowmask);
    const int kk = k0 + __popcll(bb1);
    if (kk > RCAP) return;             // handled by a straggler block
    if (m0 && pos0 < RCAP) obs[pos0] = lane;
    if (m1v && pos1 < RCAP) obs[pos1] = i1;
    if (lane >= kk && lane < RCAP) obs[lane] = 0;
    __asm__ __volatile__("" ::: "memory");

    int rows[8], cols[8];
    #pragma unroll
    for (int j = 0; j < 8; ++j) rows[j] = obs[8 * R + j];
    #pragma unroll
    for (int m = 0; m < 8; ++m) cols[m] = obs[8 * C + m];

    double T[8][8];
    #pragma unroll
    for (int j = 0; j < 8; ++j) {
        const int gr = 8 * R + j;
        #pragma unroll
        for (int m = 0; m < 8; ++m) {
            const int gc = 8 * C + m;
            double v = 0.0;
            if (gr < kk && gc < kk) {
                v = cov[rows[j] * DD + cols[m]];
                if (gr == gc) v += JITTER;
            }
            T[j][m] = v;
        }
    }

    // z_own: residual of compacted row == lane (the only row this lane
    // ever publishes).
    double z_own = 0.0;
    if (lane < kk) {
        int g = obs[lane];
        z_own = (double)(x[b * DD + g] - mu[g]);
    }

    double q_acc = 0.0;
    double dsave = 1.0;

    for (int tb = 0; tb < 8; ++tb) {
        if (8 * tb >= kk) break;                  // wave-uniform
        #pragma unroll
        for (int tc = 0; tc < 8; ++tc) {
            const int t = 8 * tb + tc;
            if (t < kk) {                         // wave-uniform
                // ---- owners publish pivot column t; lane t publishes z_t
                if (C == tb) {
                    double2* pw = (double2*)&colw[10 * R];
                    double2 w0; w0.x = T[0][tc]; w0.y = T[1][tc]; pw[0] = w0;
                    double2 w1; w1.x = T[2][tc]; w1.y = T[3][tc]; pw[1] = w1;
                    double2 w2; w2.x = T[4][tc]; w2.y = T[5][tc]; pw[2] = w2;
                    double2 w3; w3.x = T[6][tc]; w3.y = T[7][tc]; pw[3] = w3;
                }
                if (lane == t) colw[80] = z_own;
                __asm__ __volatile__("" ::: "memory");  // writes before reads

                double d   = colw[10 * tb + tc];        // broadcast
                double zt  = colw[80];                  // broadcast
                double a_own = colw[10 * R + C];        // A[lane, t]
                double inv = 1.0 / d;
                if (lane == t) dsave = d;
                q_acc = fma(zt * inv, zt, q_acc);

                double ar[8], ac[8];
                const double2* pr = (const double2*)&colw[10 * R];
                const double2* pc = (const double2*)&colw[10 * C];
                #pragma unroll
                for (int k2 = 0; k2 < 4; ++k2) {
                    double2 va = pr[k2];
                    ar[2 * k2]     = va.x;
                    ar[2 * k2 + 1] = va.y;
                    double2 vb = pc[k2];
                    ac[2 * k2]     = vb.x;
                    ac[2 * k2 + 1] = vb.y;
                }
                __asm__ __volatile__("" ::: "memory");  // reads before next writes

                #pragma unroll
                for (int j = 0; j < 8; ++j) {
                    double lj = ar[j] * inv;
                    #pragma unroll
                    for (int m = 0; m < 8; ++m)
                        T[j][m] = fma(-lj, ac[m], T[j][m]);
                }
                z_own = fma(-(a_own * inv), zt, z_own);
            }
        }
    }

    double ld = log(dsave);
    for (int off = 32; off; off >>= 1)
        ld += __shfl_down(ld, off);
    if (lane == 0)
        out[b] = (float)(0.5 * (q_acc + ld + (double)kk * LOG_2PI));
}

// ---------------------------------------------------------------------------
extern "C" void kernel_launch(void* const* d_in, const int* in_sizes, int n_in,
                              void* d_out, int out_size, void* d_ws, size_t ws_size,
                              hipStream_t stream)
{
    const float* x         = (const float*)d_in[0];
    const int*   mask      = (const int*)d_in[1];
    const float* mu        = (const float*)d_in[2];
    const float* log_diag  = (const float*)d_in[3];
    const float* lower_tri = (const float*)d_in[4];
    float* out = (float*)d_out;

    double* cov = (double*)d_ws;                         // 80000 B
    int* kkArr  = (int*)((char*)d_ws + 81920);           // Bn * 4 B

    const int Bn = in_sizes[0] / DD;
    const int scanBlocks = (Bn + 255) / 256;

    build_cov_kernel<<<NBC + scanBlocks, 256, 0, stream>>>(
        log_diag, lower_tri, mask, cov, kkArr, Bn);
    nll_fused<<<Bn + NSTRAG, 64, 0, stream>>>(
        x, mask, mu, cov, out, kkArr, Bn);
}